// Round 2
// baseline (1087.429 us; speedup 1.0000x reference)
//
#include <hip/hip_runtime.h>

#define NUM_USERS 100000
#define NUM_ITEMS 50000
#define EMB 64
#define KHOPS 3
#define NUM_EDGES 1250000
#define NNODES (NUM_USERS + NUM_ITEMS)
#define NELEM (NNODES * EMB)   // 9,600,000 floats per node-feature buffer

// ---------------------------------------------------------------------------
// 1. degree over dst (fp32 atomic counts; exact for counts < 2^24)
// ---------------------------------------------------------------------------
__global__ void deg_kernel(const int* __restrict__ dst, float* __restrict__ deg) {
    int i = blockIdx.x * blockDim.x + threadIdx.x;
    int stride = gridDim.x * blockDim.x;
    for (; i < NUM_EDGES; i += stride) {
        unsafeAtomicAdd(&deg[dst[i]], 1.0f);
    }
}

// ---------------------------------------------------------------------------
// 2. deg -> deg^{-1/2} in place (0 for isolated nodes)
// ---------------------------------------------------------------------------
__global__ void dis_kernel(float* __restrict__ deg) {
    int i = blockIdx.x * blockDim.x + threadIdx.x;
    if (i < NNODES) {
        float d = deg[i];
        deg[i] = (d > 0.0f) ? (1.0f / sqrtf(d)) : 0.0f;
    }
}

// ---------------------------------------------------------------------------
// 3. norm[e] = dis[src[e]] * dis[dst[e]]
// ---------------------------------------------------------------------------
__global__ void norm_kernel(const int* __restrict__ src, const int* __restrict__ dst,
                            const float* __restrict__ dis, float* __restrict__ norm) {
    int i = blockIdx.x * blockDim.x + threadIdx.x;
    int stride = gridDim.x * blockDim.x;
    for (; i < NUM_EDGES; i += stride) {
        norm[i] = dis[src[i]] * dis[dst[i]];
    }
}

// ---------------------------------------------------------------------------
// 4. x0 = concat(user, item); out = x0   (float4 vectorized)
// ---------------------------------------------------------------------------
__global__ void init_kernel(const float4* __restrict__ uw, const float4* __restrict__ iw,
                            float4* __restrict__ x, float4* __restrict__ out) {
    int i = blockIdx.x * blockDim.x + threadIdx.x;
    const int nuser4 = NUM_USERS * EMB / 4;
    const int ntot4  = NELEM / 4;
    if (i < ntot4) {
        float4 v = (i < nuser4) ? uw[i] : iw[i - nuser4];
        x[i]   = v;
        out[i] = v;
    }
}

// ---------------------------------------------------------------------------
// 5. edge-parallel propagation: one 64-lane group per edge, lane = emb dim.
//    Gather x[src] (256B coalesced) -> scale -> hw fp32 atomic scatter to x[dst].
// ---------------------------------------------------------------------------
__global__ void prop_kernel(const int* __restrict__ src, const int* __restrict__ dst,
                            const float* __restrict__ norm,
                            const float* __restrict__ xin, float* __restrict__ xout) {
    int lane   = threadIdx.x & (EMB - 1);
    int egrp   = (blockIdx.x * blockDim.x + threadIdx.x) >> 6;
    int egride = (gridDim.x * blockDim.x) >> 6;
    for (int e = egrp; e < NUM_EDGES; e += egride) {
        float nv = norm[e];
        if (nv != 0.0f) {               // wave-uniform within the 64-lane group
            int s = src[e];
            int d = dst[e];
            float v = nv * xin[s * EMB + lane];
            unsafeAtomicAdd(&xout[d * EMB + lane], v);
        }
    }
}

// ---------------------------------------------------------------------------
// 6. out += x   (float4)
// ---------------------------------------------------------------------------
__global__ void add_kernel(float4* __restrict__ out, const float4* __restrict__ x) {
    int i = blockIdx.x * blockDim.x + threadIdx.x;
    const int ntot4 = NELEM / 4;
    if (i < ntot4) {
        float4 o = out[i];
        float4 v = x[i];
        o.x += v.x; o.y += v.y; o.z += v.z; o.w += v.w;
        out[i] = o;
    }
}

// ---------------------------------------------------------------------------
// 7. out *= 0.25
// ---------------------------------------------------------------------------
__global__ void scale_kernel(float4* __restrict__ out) {
    int i = blockIdx.x * blockDim.x + threadIdx.x;
    const int ntot4 = NELEM / 4;
    if (i < ntot4) {
        float4 o = out[i];
        o.x *= 0.25f; o.y *= 0.25f; o.z *= 0.25f; o.w *= 0.25f;
        out[i] = o;
    }
}

extern "C" void kernel_launch(void* const* d_in, const int* in_sizes, int n_in,
                              void* d_out, int out_size, void* d_ws, size_t ws_size,
                              hipStream_t stream) {
    const float* uw  = (const float*)d_in[0];   // [NUM_USERS, EMB]
    const float* iw  = (const float*)d_in[1];   // [NUM_ITEMS, EMB]
    const int*   ei  = (const int*)d_in[2];     // [2, NUM_EDGES]
    const int*   src = ei;
    const int*   dst = ei + NUM_EDGES;

    float* out = (float*)d_out;                 // [NNODES, EMB] flat

    // workspace layout
    char* ws = (char*)d_ws;
    float* xbuf0 = (float*)ws;                                  // NELEM floats
    float* xbuf1 = xbuf0 + NELEM;                               // NELEM floats
    float* deg   = xbuf1 + NELEM;                               // NNODES floats (becomes dis)
    float* norm  = deg + NNODES;                                // NUM_EDGES floats

    const int B = 256;

    // degree
    hipMemsetAsync(deg, 0, NNODES * sizeof(float), stream);
    deg_kernel<<<2048, B, 0, stream>>>(dst, deg);
    dis_kernel<<<(NNODES + B - 1) / B, B, 0, stream>>>(deg);
    norm_kernel<<<2048, B, 0, stream>>>(src, dst, deg, norm);

    // x0, out = x0
    const int ntot4 = NELEM / 4;
    init_kernel<<<(ntot4 + B - 1) / B, B, 0, stream>>>(
        (const float4*)uw, (const float4*)iw, (float4*)xbuf0, (float4*)out);

    // K hops, ping-pong
    float* xcur = xbuf0;
    float* xnxt = xbuf1;
    for (int k = 0; k < KHOPS; ++k) {
        hipMemsetAsync(xnxt, 0, NELEM * sizeof(float), stream);
        prop_kernel<<<8192, B, 0, stream>>>(src, dst, norm, xcur, xnxt);
        add_kernel<<<(ntot4 + B - 1) / B, B, 0, stream>>>((float4*)out, (const float4*)xnxt);
        float* t = xcur; xcur = xnxt; xnxt = t;
    }

    scale_kernel<<<(ntot4 + B - 1) / B, B, 0, stream>>>((float4*)out);
}

// Round 3
// 627.181 us; speedup vs baseline: 1.7338x; 1.7338x over previous
//
#include <hip/hip_runtime.h>

#define NUM_USERS 100000
#define NUM_ITEMS 50000
#define EMB 64
#define NUM_EDGES 1250000
#define NNODES (NUM_USERS + NUM_ITEMS)
#define NELEM (NNODES * EMB)      // 9,600,000 floats
#define SCAN_CHUNK 1024
#define NBLK_SCAN ((NNODES + SCAN_CHUNK - 1) / SCAN_CHUNK)   // 147

// ---------------------------------------------------------------------------
// 1. histogram over dst (int atomics)
// ---------------------------------------------------------------------------
__global__ void hist_kernel(const int* __restrict__ dst, int* __restrict__ counts) {
    int i = blockIdx.x * blockDim.x + threadIdx.x;
    int stride = gridDim.x * blockDim.x;
    for (; i < NUM_EDGES; i += stride) {
        atomicAdd(&counts[dst[i]], 1);
    }
}

// ---------------------------------------------------------------------------
// 2a. per-block sums of 1024-element chunks
// ---------------------------------------------------------------------------
__global__ void scan1_kernel(const int* __restrict__ counts, int* __restrict__ blksum) {
    __shared__ int lds[256];
    int base = blockIdx.x * SCAN_CHUNK;
    int t = threadIdx.x;
    int s = 0;
#pragma unroll
    for (int j = 0; j < 4; ++j) {
        int i = base + t * 4 + j;
        if (i < NNODES) s += counts[i];
    }
    lds[t] = s;
    __syncthreads();
    for (int off = 128; off > 0; off >>= 1) {
        if (t < off) lds[t] += lds[t + off];
        __syncthreads();
    }
    if (t == 0) blksum[blockIdx.x] = lds[0];
}

// ---------------------------------------------------------------------------
// 2b. exclusive scan of block sums (NBLK_SCAN <= 256), one block
// ---------------------------------------------------------------------------
__global__ void scan2_kernel(int* __restrict__ blksum) {
    __shared__ int lds[256];
    int t = threadIdx.x;
    int v = (t < NBLK_SCAN) ? blksum[t] : 0;
    lds[t] = v;
    __syncthreads();
    for (int off = 1; off < 256; off <<= 1) {
        int add = (t >= off) ? lds[t - off] : 0;
        __syncthreads();
        lds[t] += add;
        __syncthreads();
    }
    if (t < NBLK_SCAN) blksum[t] = lds[t] - v;   // exclusive
}

// ---------------------------------------------------------------------------
// 2c. per-element exclusive offsets + dis + cursor (cursor overwrites counts)
// ---------------------------------------------------------------------------
__global__ void scan3_kernel(int* __restrict__ counts /* in: counts, out: cursor */,
                             const int* __restrict__ blksum,
                             int* __restrict__ offs, float* __restrict__ dis) {
    __shared__ int lds[256];
    int base = blockIdx.x * SCAN_CHUNK;
    int t = threadIdx.x;
    int c[4];
    int s = 0;
#pragma unroll
    for (int j = 0; j < 4; ++j) {
        int i = base + t * 4 + j;
        c[j] = (i < NNODES) ? counts[i] : 0;
        s += c[j];
    }
    lds[t] = s;
    __syncthreads();
    for (int off = 1; off < 256; off <<= 1) {
        int add = (t >= off) ? lds[t - off] : 0;
        __syncthreads();
        lds[t] += add;
        __syncthreads();
    }
    int run = blksum[blockIdx.x] + lds[t] - s;   // exclusive prefix of first elem
#pragma unroll
    for (int j = 0; j < 4; ++j) {
        int i = base + t * 4 + j;
        if (i < NNODES) {
            offs[i] = run;
            dis[i]  = (c[j] > 0) ? (1.0f / sqrtf((float)c[j])) : 0.0f;
            counts[i] = run;                      // becomes scatter cursor
            run += c[j];
        }
    }
}

// ---------------------------------------------------------------------------
// 3. scatter edges into CSR slots: entries[pos] = {src, norm}
// ---------------------------------------------------------------------------
__global__ void scatter_kernel(const int* __restrict__ src, const int* __restrict__ dst,
                               const float* __restrict__ dis,
                               int* __restrict__ cursor, int2* __restrict__ entries) {
    int i = blockIdx.x * blockDim.x + threadIdx.x;
    int stride = gridDim.x * blockDim.x;
    for (; i < NUM_EDGES; i += stride) {
        int s = src[i];
        int d = dst[i];
        int pos = atomicAdd(&cursor[d], 1);
        entries[pos] = make_int2(s, __float_as_int(dis[s] * dis[d]));
    }
}

// ---------------------------------------------------------------------------
// 4. pull propagation: one 64-lane wave per dst node, lane = emb dim.
//    FINAL=true additionally fuses out = 0.25*(x0 + x1 + x2 + acc).
//    Gather source is (xu, xi): for hop 1 these are the two weight tables;
//    for later hops pass xu = xprev, xi = xprev + NUM_USERS*EMB.
// ---------------------------------------------------------------------------
template <bool FINAL>
__global__ __launch_bounds__(256)
void pull_kernel(const int2* __restrict__ entries, const int* __restrict__ offs,
                 const int* __restrict__ ends,
                 const float* __restrict__ xu, const float* __restrict__ xi,
                 const float* __restrict__ uw, const float* __restrict__ iw,
                 const float* __restrict__ x1,
                 float* __restrict__ xout) {
    int gid  = blockIdx.x * blockDim.x + threadIdx.x;
    int n    = gid >> 6;
    int lane = gid & 63;
    if (n >= NNODES) return;

    int beg = offs[n];
    int end = ends[n];
    float acc = 0.0f;
    for (int p = beg; p < end; ++p) {
        int2 en = entries[p];                     // uniform 8B load (broadcast)
        const float* row = (en.x < NUM_USERS)
                               ? (xu + (size_t)en.x * EMB)
                               : (xi + (size_t)(en.x - NUM_USERS) * EMB);
        acc = fmaf(__int_as_float(en.y), row[lane], acc);
    }

    size_t o = (size_t)n * EMB + lane;
    if (FINAL) {
        // x2 row = gather-source buffer's own row n
        float x2v = (n < NUM_USERS) ? xu[o] : xi[(size_t)(n - NUM_USERS) * EMB + lane];
        float x0v = (n < NUM_USERS) ? uw[o] : iw[(size_t)(n - NUM_USERS) * EMB + lane];
        xout[o] = 0.25f * (x0v + x1[o] + x2v + acc);
    } else {
        xout[o] = acc;
    }
}

extern "C" void kernel_launch(void* const* d_in, const int* in_sizes, int n_in,
                              void* d_out, int out_size, void* d_ws, size_t ws_size,
                              hipStream_t stream) {
    const float* uw  = (const float*)d_in[0];    // [NUM_USERS, EMB]
    const float* iw  = (const float*)d_in[1];    // [NUM_ITEMS, EMB]
    const int*   ei  = (const int*)d_in[2];      // [2, NUM_EDGES] (int32 on device)
    const int*   src = ei;
    const int*   dst = ei + NUM_EDGES;

    float* out = (float*)d_out;                  // [NNODES, EMB] flat

    // workspace layout (~88.6 MB)
    char*  ws      = (char*)d_ws;
    float* xa      = (float*)ws;                              // NELEM floats (x1)
    float* xb      = xa + NELEM;                              // NELEM floats (x2)
    int2*  entries = (int2*)(xb + NELEM);                     // NUM_EDGES int2
    int*   counts  = (int*)(entries + NUM_EDGES);             // NNODES (-> cursor)
    int*   offs    = counts + NNODES;                         // NNODES
    float* dis     = (float*)(offs + NNODES);                 // NNODES
    int*   blksum  = (int*)(dis + NNODES);                    // NBLK_SCAN

    const int B = 256;

    // --- CSR build ---
    hipMemsetAsync(counts, 0, NNODES * sizeof(int), stream);
    hist_kernel<<<2048, B, 0, stream>>>(dst, counts);
    scan1_kernel<<<NBLK_SCAN, B, 0, stream>>>(counts, blksum);
    scan2_kernel<<<1, B, 0, stream>>>(blksum);
    scan3_kernel<<<NBLK_SCAN, B, 0, stream>>>(counts, blksum, offs, dis);
    scatter_kernel<<<2048, B, 0, stream>>>(src, dst, dis, counts /*cursor*/, entries);
    // after scatter: counts[n] == offs[n] + deg[n] == end offset

    // --- K=3 pull hops ---
    const int pull_blocks = (NNODES * EMB + B - 1) / B;       // 37500
    const float* x1u = xa;
    const float* x1i = xa + (size_t)NUM_USERS * EMB;
    const float* x2u = xb;
    const float* x2i = xb + (size_t)NUM_USERS * EMB;

    // hop 1: x1 = A x0  (gather from weight tables)
    pull_kernel<false><<<pull_blocks, B, 0, stream>>>(
        entries, offs, counts, uw, iw, nullptr, nullptr, nullptr, xa);
    // hop 2: x2 = A x1
    pull_kernel<false><<<pull_blocks, B, 0, stream>>>(
        entries, offs, counts, x1u, x1i, nullptr, nullptr, nullptr, xb);
    // hop 3 fused: out = 0.25*(x0 + x1 + x2 + A x2)
    pull_kernel<true><<<pull_blocks, B, 0, stream>>>(
        entries, offs, counts, x2u, x2i, uw, iw, xa, out);
}

// Round 4
// 438.118 us; speedup vs baseline: 2.4820x; 1.4315x over previous
//
#include <hip/hip_runtime.h>

#define NUM_USERS 100000
#define NUM_ITEMS 50000
#define EMB 64
#define NUM_EDGES 1250000
#define NNODES (NUM_USERS + NUM_ITEMS)
#define NELEM (NNODES * EMB)      // 9,600,000 floats
#define SCAN_CHUNK 1024
#define NBLK_SCAN ((NNODES + SCAN_CHUNK - 1) / SCAN_CHUNK)   // 147

// ---------------------------------------------------------------------------
// 1. histogram over dst (int atomics), int4-vectorized edge reads
// ---------------------------------------------------------------------------
__global__ void hist_kernel(const int4* __restrict__ dst4, int* __restrict__ counts) {
    int i = blockIdx.x * blockDim.x + threadIdx.x;
    if (i < NUM_EDGES / 4) {
        int4 d = dst4[i];
        atomicAdd(&counts[d.x], 1);
        atomicAdd(&counts[d.y], 1);
        atomicAdd(&counts[d.z], 1);
        atomicAdd(&counts[d.w], 1);
    }
}

// ---------------------------------------------------------------------------
// 2a. per-block sums of 1024-element chunks
// ---------------------------------------------------------------------------
__global__ void scan1_kernel(const int* __restrict__ counts, int* __restrict__ blksum) {
    __shared__ int lds[256];
    int base = blockIdx.x * SCAN_CHUNK;
    int t = threadIdx.x;
    int s = 0;
#pragma unroll
    for (int j = 0; j < 4; ++j) {
        int i = base + t * 4 + j;
        if (i < NNODES) s += counts[i];
    }
    lds[t] = s;
    __syncthreads();
    for (int off = 128; off > 0; off >>= 1) {
        if (t < off) lds[t] += lds[t + off];
        __syncthreads();
    }
    if (t == 0) blksum[blockIdx.x] = lds[0];
}

// ---------------------------------------------------------------------------
// 2b. exclusive scan of block sums (NBLK_SCAN <= 256), one block
// ---------------------------------------------------------------------------
__global__ void scan2_kernel(int* __restrict__ blksum) {
    __shared__ int lds[256];
    int t = threadIdx.x;
    int v = (t < NBLK_SCAN) ? blksum[t] : 0;
    lds[t] = v;
    __syncthreads();
    for (int off = 1; off < 256; off <<= 1) {
        int add = (t >= off) ? lds[t - off] : 0;
        __syncthreads();
        lds[t] += add;
        __syncthreads();
    }
    if (t < NBLK_SCAN) blksum[t] = lds[t] - v;   // exclusive
}

// ---------------------------------------------------------------------------
// 2c. offsets + per-node scale tables + scatter cursor (overwrites counts)
//     dis = deg^{-1/2}, invdeg = 1/deg, rdis = deg^{+1/2}  (0 when deg==0)
// ---------------------------------------------------------------------------
__global__ void scan3_kernel(int* __restrict__ counts /* in: counts, out: cursor */,
                             const int* __restrict__ blksum,
                             int* __restrict__ offs, float* __restrict__ dis,
                             float* __restrict__ invdeg, float* __restrict__ rdis) {
    __shared__ int lds[256];
    int base = blockIdx.x * SCAN_CHUNK;
    int t = threadIdx.x;
    int c[4];
    int s = 0;
#pragma unroll
    for (int j = 0; j < 4; ++j) {
        int i = base + t * 4 + j;
        c[j] = (i < NNODES) ? counts[i] : 0;
        s += c[j];
    }
    lds[t] = s;
    __syncthreads();
    for (int off = 1; off < 256; off <<= 1) {
        int add = (t >= off) ? lds[t - off] : 0;
        __syncthreads();
        lds[t] += add;
        __syncthreads();
    }
    int run = blksum[blockIdx.x] + lds[t] - s;   // exclusive prefix of first elem
#pragma unroll
    for (int j = 0; j < 4; ++j) {
        int i = base + t * 4 + j;
        if (i < NNODES) {
            float fc = (float)c[j];
            offs[i]   = run;
            dis[i]    = (c[j] > 0) ? (1.0f / sqrtf(fc)) : 0.0f;
            invdeg[i] = (c[j] > 0) ? (1.0f / fc) : 0.0f;
            rdis[i]   = (c[j] > 0) ? sqrtf(fc) : 0.0f;
            counts[i] = run;                      // becomes scatter cursor
            run += c[j];
        }
    }
}

// ---------------------------------------------------------------------------
// 3. scatter src indices into CSR slots (entries are 4B now — no norm)
// ---------------------------------------------------------------------------
__global__ void scatter_kernel(const int4* __restrict__ src4, const int4* __restrict__ dst4,
                               int* __restrict__ cursor, int* __restrict__ entries) {
    int i = blockIdx.x * blockDim.x + threadIdx.x;
    if (i < NUM_EDGES / 4) {
        int4 s = src4[i];
        int4 d = dst4[i];
        entries[atomicAdd(&cursor[d.x], 1)] = s.x;
        entries[atomicAdd(&cursor[d.y], 1)] = s.y;
        entries[atomicAdd(&cursor[d.z], 1)] = s.z;
        entries[atomicAdd(&cursor[d.w], 1)] = s.w;
    }
}

// ---------------------------------------------------------------------------
// 4. y0 = dis ⊙ concat(uw, iw)   (float4; written into d_out as scratch)
// ---------------------------------------------------------------------------
__global__ void y0_kernel(const float4* __restrict__ uw, const float4* __restrict__ iw,
                          const float* __restrict__ dis, float4* __restrict__ y0) {
    int i = blockIdx.x * blockDim.x + threadIdx.x;
    const int nuser4 = NUM_USERS * EMB / 4;
    if (i < NELEM / 4) {
        float4 v = (i < nuser4) ? uw[i] : iw[i - nuser4];
        float dd = dis[i >> 4];                  // node index = i/(EMB/4)
        v.x *= dd; v.y *= dd; v.z *= dd; v.w *= dd;
        y0[i] = v;
    }
}

// ---------------------------------------------------------------------------
// 5. pull hop: yout[d] = invdeg[d] * Σ_{s∈N(d)} yin[s]
//    One wave per node; entry indices batch-loaded then __shfl-broadcast;
//    4-wide unroll = 4 outstanding 256B gathers per wave.
// ---------------------------------------------------------------------------
__global__ __launch_bounds__(256)
void pull_kernel(const int* __restrict__ entries, const int* __restrict__ offs,
                 const int* __restrict__ ends, const float* __restrict__ invdeg,
                 const float* __restrict__ yin, float* __restrict__ yout) {
    int gid  = blockIdx.x * blockDim.x + threadIdx.x;
    int n    = gid >> 6;
    int lane = gid & 63;
    if (n >= NNODES) return;

    int beg = offs[n];
    int end = ends[n];
    float a0 = 0.0f, a1 = 0.0f, a2 = 0.0f, a3 = 0.0f;
    for (int pb = beg; pb < end; pb += 64) {
        int m = end - pb; if (m > 64) m = 64;
        int ent = (pb + lane < end) ? entries[pb + lane] : 0;
        int j = 0;
        for (; j + 4 <= m; j += 4) {
            int s0 = __shfl(ent, j);
            int s1 = __shfl(ent, j + 1);
            int s2 = __shfl(ent, j + 2);
            int s3 = __shfl(ent, j + 3);
            a0 += yin[(size_t)s0 * EMB + lane];
            a1 += yin[(size_t)s1 * EMB + lane];
            a2 += yin[(size_t)s2 * EMB + lane];
            a3 += yin[(size_t)s3 * EMB + lane];
        }
        for (; j < m; ++j) {
            int s0 = __shfl(ent, j);
            a0 += yin[(size_t)s0 * EMB + lane];
        }
    }
    yout[(size_t)n * EMB + lane] = ((a0 + a1) + (a2 + a3)) * invdeg[n];
}

// ---------------------------------------------------------------------------
// 6. final fused hop: out = 0.25*(x0 + rdis*(y1+y2) + dis*Σ y2[s])
//    (x3 = rdis*invdeg*Σ y2 = dis*Σ y2)
// ---------------------------------------------------------------------------
__global__ __launch_bounds__(256)
void final_kernel(const int* __restrict__ entries, const int* __restrict__ offs,
                  const int* __restrict__ ends,
                  const float* __restrict__ dis, const float* __restrict__ rdis,
                  const float* __restrict__ y1, const float* __restrict__ y2,
                  const float* __restrict__ uw, const float* __restrict__ iw,
                  float* __restrict__ out) {
    int gid  = blockIdx.x * blockDim.x + threadIdx.x;
    int n    = gid >> 6;
    int lane = gid & 63;
    if (n >= NNODES) return;

    int beg = offs[n];
    int end = ends[n];
    float a0 = 0.0f, a1 = 0.0f, a2 = 0.0f, a3 = 0.0f;
    for (int pb = beg; pb < end; pb += 64) {
        int m = end - pb; if (m > 64) m = 64;
        int ent = (pb + lane < end) ? entries[pb + lane] : 0;
        int j = 0;
        for (; j + 4 <= m; j += 4) {
            int s0 = __shfl(ent, j);
            int s1 = __shfl(ent, j + 1);
            int s2 = __shfl(ent, j + 2);
            int s3 = __shfl(ent, j + 3);
            a0 += y2[(size_t)s0 * EMB + lane];
            a1 += y2[(size_t)s1 * EMB + lane];
            a2 += y2[(size_t)s2 * EMB + lane];
            a3 += y2[(size_t)s3 * EMB + lane];
        }
        for (; j < m; ++j) {
            int s0 = __shfl(ent, j);
            a0 += y2[(size_t)s0 * EMB + lane];
        }
    }
    float acc = (a0 + a1) + (a2 + a3);

    size_t o = (size_t)n * EMB + lane;
    float x0v = (n < NUM_USERS) ? uw[o] : iw[o - (size_t)NUM_USERS * EMB];
    out[o] = 0.25f * (x0v + rdis[n] * (y1[o] + y2[o]) + dis[n] * acc);
}

extern "C" void kernel_launch(void* const* d_in, const int* in_sizes, int n_in,
                              void* d_out, int out_size, void* d_ws, size_t ws_size,
                              hipStream_t stream) {
    const float* uw  = (const float*)d_in[0];    // [NUM_USERS, EMB]
    const float* iw  = (const float*)d_in[1];    // [NUM_ITEMS, EMB]
    const int*   ei  = (const int*)d_in[2];      // [2, NUM_EDGES]
    const int*   src = ei;
    const int*   dst = ei + NUM_EDGES;

    float* out = (float*)d_out;                  // [NNODES, EMB]; doubles as y0 scratch

    // workspace layout (~84 MB)
    char*  ws      = (char*)d_ws;
    float* y1      = (float*)ws;                              // NELEM floats
    float* y2      = y1 + NELEM;                              // NELEM floats
    int*   entries = (int*)(y2 + NELEM);                      // NUM_EDGES ints
    int*   counts  = entries + NUM_EDGES;                     // NNODES (-> cursor -> ends)
    int*   offs    = counts + NNODES;                         // NNODES
    float* dis     = (float*)(offs + NNODES);                 // NNODES
    float* invdeg  = dis + NNODES;                            // NNODES
    float* rdis    = invdeg + NNODES;                         // NNODES
    int*   blksum  = (int*)(rdis + NNODES);                   // NBLK_SCAN

    const int B = 256;
    const int eblk = (NUM_EDGES / 4 + B - 1) / B;             // 1221

    // --- CSR build + scale tables ---
    hipMemsetAsync(counts, 0, NNODES * sizeof(int), stream);
    hist_kernel<<<eblk, B, 0, stream>>>((const int4*)dst, counts);
    scan1_kernel<<<NBLK_SCAN, B, 0, stream>>>(counts, blksum);
    scan2_kernel<<<1, B, 0, stream>>>(blksum);
    scan3_kernel<<<NBLK_SCAN, B, 0, stream>>>(counts, blksum, offs, dis, invdeg, rdis);
    scatter_kernel<<<eblk, B, 0, stream>>>((const int4*)src, (const int4*)dst,
                                           counts /*cursor*/, entries);
    // after scatter: counts[n] == end offset

    // --- y0 = dis ⊙ x0 (into d_out as scratch) ---
    y0_kernel<<<(NELEM / 4 + B - 1) / B, B, 0, stream>>>(
        (const float4*)uw, (const float4*)iw, dis, (float4*)out);

    // --- hops ---
    const int pull_blocks = (NNODES * EMB + B - 1) / B;       // 37500
    pull_kernel<<<pull_blocks, B, 0, stream>>>(entries, offs, counts, invdeg, out, y1);
    pull_kernel<<<pull_blocks, B, 0, stream>>>(entries, offs, counts, invdeg, y1, y2);
    final_kernel<<<pull_blocks, B, 0, stream>>>(entries, offs, counts, dis, rdis,
                                                y1, y2, uw, iw, out);
}

// Round 9
// 375.428 us; speedup vs baseline: 2.8965x; 1.1670x over previous
//
#include <hip/hip_runtime.h>

#define NUM_USERS 100000
#define NUM_ITEMS 50000
#define EMB 64
#define NUM_EDGES 1250000
#define NNODES (NUM_USERS + NUM_ITEMS)
#define NELEM (NNODES * EMB)      // 9,600,000 floats
#define SCAN_CHUNK 1024
#define NBLK_SCAN ((NNODES + SCAN_CHUNK - 1) / SCAN_CHUNK)   // 147

// ---------------------------------------------------------------------------
// 1. fused histogram + per-edge rank: rank[e] = position within dst bucket
// ---------------------------------------------------------------------------
__global__ void hist_rank_c(const int4* __restrict__ dst4, int* __restrict__ counts,
                            int4* __restrict__ rank4) {
    int i = blockIdx.x * blockDim.x + threadIdx.x;
    if (i < NUM_EDGES / 4) {
        int4 d = dst4[i];
        int4 r;
        r.x = atomicAdd(&counts[d.x], 1);
        r.y = atomicAdd(&counts[d.y], 1);
        r.z = atomicAdd(&counts[d.z], 1);
        r.w = atomicAdd(&counts[d.w], 1);
        rank4[i] = r;
    }
}

// ---------------------------------------------------------------------------
// 2a. per-block sums of 1024-element chunks
// ---------------------------------------------------------------------------
__global__ void scan1_c(const int* __restrict__ counts, int* __restrict__ blksum) {
    __shared__ int lds[256];
    int base = blockIdx.x * SCAN_CHUNK;
    int t = threadIdx.x;
    int s = 0;
#pragma unroll
    for (int j = 0; j < 4; ++j) {
        int i = base + t * 4 + j;
        if (i < NNODES) s += counts[i];
    }
    lds[t] = s;
    __syncthreads();
    for (int off = 128; off > 0; off >>= 1) {
        if (t < off) lds[t] += lds[t + off];
        __syncthreads();
    }
    if (t == 0) blksum[blockIdx.x] = lds[0];
}

// ---------------------------------------------------------------------------
// 2b. exclusive scan of block sums (NBLK_SCAN <= 256), one block
// ---------------------------------------------------------------------------
__global__ void scan2_c(int* __restrict__ blksum) {
    __shared__ int lds[256];
    int t = threadIdx.x;
    int v = (t < NBLK_SCAN) ? blksum[t] : 0;
    lds[t] = v;
    __syncthreads();
    for (int off = 1; off < 256; off <<= 1) {
        int add = (t >= off) ? lds[t - off] : 0;
        __syncthreads();
        lds[t] += add;
        __syncthreads();
    }
    if (t < NBLK_SCAN) blksum[t] = lds[t] - v;   // exclusive
}

// ---------------------------------------------------------------------------
// 2c. offsets + per-node scale tables (counts preserved as degree)
//     dis = deg^{-1/2}, invdeg = 1/deg, rdis = deg^{+1/2}  (0 when deg==0)
// ---------------------------------------------------------------------------
__global__ void scan3_c(const int* __restrict__ counts, const int* __restrict__ blksum,
                        int* __restrict__ offs, float* __restrict__ dis,
                        float* __restrict__ invdeg, float* __restrict__ rdis) {
    __shared__ int lds[256];
    int base = blockIdx.x * SCAN_CHUNK;
    int t = threadIdx.x;
    int c[4];
    int s = 0;
#pragma unroll
    for (int j = 0; j < 4; ++j) {
        int i = base + t * 4 + j;
        c[j] = (i < NNODES) ? counts[i] : 0;
        s += c[j];
    }
    lds[t] = s;
    __syncthreads();
    for (int off = 1; off < 256; off <<= 1) {
        int add = (t >= off) ? lds[t - off] : 0;
        __syncthreads();
        lds[t] += add;
        __syncthreads();
    }
    int run = blksum[blockIdx.x] + lds[t] - s;   // exclusive prefix of first elem
#pragma unroll
    for (int j = 0; j < 4; ++j) {
        int i = base + t * 4 + j;
        if (i < NNODES) {
            float fc = (float)c[j];
            offs[i]   = run;
            dis[i]    = (c[j] > 0) ? (1.0f / sqrtf(fc)) : 0.0f;
            invdeg[i] = (c[j] > 0) ? (1.0f / fc) : 0.0f;
            rdis[i]   = (c[j] > 0) ? sqrtf(fc) : 0.0f;
            run += c[j];
        }
    }
}

// ---------------------------------------------------------------------------
// 3. atomic-free scatter: entries[offs[dst]+rank] = src
// ---------------------------------------------------------------------------
__global__ void scatter_c(const int4* __restrict__ src4, const int4* __restrict__ dst4,
                          const int4* __restrict__ rank4, const int* __restrict__ offs,
                          int* __restrict__ entries) {
    int i = blockIdx.x * blockDim.x + threadIdx.x;
    if (i < NUM_EDGES / 4) {
        int4 s = src4[i];
        int4 d = dst4[i];
        int4 r = rank4[i];
        entries[offs[d.x] + r.x] = s.x;
        entries[offs[d.y] + r.y] = s.y;
        entries[offs[d.z] + r.z] = s.z;
        entries[offs[d.w] + r.w] = s.w;
    }
}

// ---------------------------------------------------------------------------
// 4. y0 = dis ⊙ concat(uw, iw)   (fp32, float4; written into d_out as scratch)
// ---------------------------------------------------------------------------
__global__ void y0_c(const float4* __restrict__ uw4, const float4* __restrict__ iw4,
                     const float* __restrict__ dis, float4* __restrict__ y0) {
    int i = blockIdx.x * blockDim.x + threadIdx.x;
    const int nuser4 = NUM_USERS * EMB / 4;
    if (i < NELEM / 4) {
        float4 v = (i < nuser4) ? uw4[i] : iw4[i - nuser4];
        float w = dis[i >> 4];                    // node = i / (EMB/4)
        v.x *= w; v.y *= w; v.z *= w; v.w *= w;
        y0[i] = v;
    }
}

// ---------------------------------------------------------------------------
// 5. pull hop (fp32). One wave per node; grp = lane/16 picks the edge slot,
//    chunk = lane%16 picks 4 emb dims via one float4 load.
//    INNER LOOP IS WAVE-UNIFORM: `it` bounds depend only on rem (uniform per
//    wave), so every __shfl executes with all 64 lanes active. The previous
//    per-group loop (p = grp; p < rem; p += 16) had divergent trip counts,
//    making later shfls read exec-masked-off lanes -> undefined (the ~5.5e-4
//    absmax failures of rounds 5/7/8).
//    FINAL fuses out = 0.25*(x0 + rdis*(y1+y2) + dis*Σ y2[s]).
// ---------------------------------------------------------------------------
__device__ __forceinline__ void gacc_c(float4& a, const float4* __restrict__ y,
                                       int s, int chunk) {
    float4 v = y[((size_t)s << 4) + chunk];       // row s = 16 float4s (256B)
    a.x += v.x; a.y += v.y; a.z += v.z; a.w += v.w;
}

template <bool FINAL>
__global__ __launch_bounds__(256)
void pull_c(const int* __restrict__ entries, const int* __restrict__ offs,
            const int* __restrict__ deg, const float* __restrict__ invdeg,
            const float4* __restrict__ yin,         // gather source
            const float* __restrict__ dis, const float* __restrict__ rdis,
            const float4* __restrict__ y1,          // FINAL only
            const float* __restrict__ uw, const float* __restrict__ iw,
            float4* __restrict__ out) {
    int gid  = blockIdx.x * blockDim.x + threadIdx.x;
    int n    = gid >> 6;
    if (n >= NNODES) return;
    int lane  = gid & 63;
    int grp   = lane >> 4;
    int chunk = lane & 15;

    const int* ebase = entries + offs[n];
    int dg = deg[n];                              // wave-uniform

    float4 a0 = {0,0,0,0}, a1 = {0,0,0,0}, a2 = {0,0,0,0}, a3 = {0,0,0,0};

    for (int base = 0; base < dg; base += 64) {   // uniform
        int rem = dg - base; if (rem > 64) rem = 64;   // uniform
        int ent = 0;
        if (lane < rem) ent = ebase[base + lane];
        for (int it = 0; it < rem; it += 16) {    // uniform trip count
            int p = it + grp;                     // group g handles p ≡ g (mod 4)
            int s0 = __shfl(ent, p);              // all 64 lanes active here
            int s1 = __shfl(ent, p + 4);
            int s2 = __shfl(ent, p + 8);
            int s3 = __shfl(ent, p + 12);         // max index 48+3+12 = 63
            if (p      < rem) gacc_c(a0, yin, s0, chunk);
            if (p + 4  < rem) gacc_c(a1, yin, s1, chunk);
            if (p + 8  < rem) gacc_c(a2, yin, s2, chunk);
            if (p + 12 < rem) gacc_c(a3, yin, s3, chunk);
        }
    }

    float4 a;
    a.x = (a0.x + a1.x) + (a2.x + a3.x);
    a.y = (a0.y + a1.y) + (a2.y + a3.y);
    a.z = (a0.z + a1.z) + (a2.z + a3.z);
    a.w = (a0.w + a1.w) + (a2.w + a3.w);
    a.x += __shfl_xor(a.x, 16); a.y += __shfl_xor(a.y, 16);
    a.z += __shfl_xor(a.z, 16); a.w += __shfl_xor(a.w, 16);
    a.x += __shfl_xor(a.x, 32); a.y += __shfl_xor(a.y, 32);
    a.z += __shfl_xor(a.z, 32); a.w += __shfl_xor(a.w, 32);

    if (lane < 16) {
        size_t ro = ((size_t)n << 4) + chunk;     // float4 index
        if (FINAL) {
            const float* xrow = (n < NUM_USERS) ? uw + ((size_t)n << 6)
                                                : iw + ((size_t)(n - NUM_USERS) << 6);
            float4 x0v = *(const float4*)(xrow + (chunk << 2));
            float4 b = y1[ro];
            float4 c = yin[ro];                   // yin == y2 in the final hop
            float rd = rdis[n], di = dis[n];
            float4 o;
            o.x = 0.25f * (x0v.x + rd * (b.x + c.x) + di * a.x);
            o.y = 0.25f * (x0v.y + rd * (b.y + c.y) + di * a.y);
            o.z = 0.25f * (x0v.z + rd * (b.z + c.z) + di * a.z);
            o.w = 0.25f * (x0v.w + rd * (b.w + c.w) + di * a.w);
            out[ro] = o;
        } else {
            float iv = invdeg[n];
            a.x *= iv; a.y *= iv; a.z *= iv; a.w *= iv;
            out[ro] = a;
        }
    }
}

extern "C" void kernel_launch(void* const* d_in, const int* in_sizes, int n_in,
                              void* d_out, int out_size, void* d_ws, size_t ws_size,
                              hipStream_t stream) {
    const float* uw  = (const float*)d_in[0];    // [NUM_USERS, EMB]
    const float* iw  = (const float*)d_in[1];    // [NUM_ITEMS, EMB]
    const int*   ei  = (const int*)d_in[2];      // [2, NUM_EDGES]
    const int*   src = ei;
    const int*   dst = ei + NUM_EDGES;

    float* out = (float*)d_out;                  // [NNODES, EMB]; doubles as y0 scratch

    // workspace layout (~84.3 MB)
    char*  ws      = (char*)d_ws;
    float* y1      = (float*)ws;                              // NELEM floats (38.4 MB)
    float* y2      = y1 + NELEM;                              // NELEM floats (38.4 MB)
    int*   entries = (int*)(y2 + NELEM);                      // NUM_EDGES ints (5 MB)
    int*   counts  = entries + NUM_EDGES;                     // NNODES (stays = degree)
    int*   offs    = counts + NNODES;                         // NNODES
    float* dis     = (float*)(offs + NNODES);                 // NNODES
    float* invdeg  = dis + NNODES;                            // NNODES
    float* rdis    = invdeg + NNODES;                         // NNODES
    int*   blksum  = (int*)(rdis + NNODES);                   // NBLK_SCAN
    int*   rank    = (int*)y1;     // alias: consumed by scatter_c before y1 written

    const int B = 256;
    const int eblk = (NUM_EDGES / 4 + B - 1) / B;             // 1221

    // --- CSR build (rank-fused, atomic-free scatter) ---
    hipMemsetAsync(counts, 0, NNODES * sizeof(int), stream);
    hist_rank_c<<<eblk, B, 0, stream>>>((const int4*)dst, counts, (int4*)rank);
    scan1_c<<<NBLK_SCAN, B, 0, stream>>>(counts, blksum);
    scan2_c<<<1, B, 0, stream>>>(blksum);
    scan3_c<<<NBLK_SCAN, B, 0, stream>>>(counts, blksum, offs, dis, invdeg, rdis);
    scatter_c<<<eblk, B, 0, stream>>>((const int4*)src, (const int4*)dst,
                                      (const int4*)rank, offs, entries);

    // --- y0 = dis ⊙ x0 (into d_out as scratch) ---
    y0_c<<<(NELEM / 4 + B - 1) / B, B, 0, stream>>>(
        (const float4*)uw, (const float4*)iw, dis, (float4*)out);

    // --- hops (one wave per node) ---
    const int pull_blocks = (NNODES * 64) / B;                // 37500
    pull_c<false><<<pull_blocks, B, 0, stream>>>(
        entries, offs, counts, invdeg, (const float4*)out, dis, rdis,
        nullptr, nullptr, nullptr, (float4*)y1);
    pull_c<false><<<pull_blocks, B, 0, stream>>>(
        entries, offs, counts, invdeg, (const float4*)y1, dis, rdis,
        nullptr, nullptr, nullptr, (float4*)y2);
    pull_c<true><<<pull_blocks, B, 0, stream>>>(
        entries, offs, counts, invdeg, (const float4*)y2, dis, rdis,
        (const float4*)y1, uw, iw, (float4*)out);
}

// Round 10
// 327.562 us; speedup vs baseline: 3.3198x; 1.1461x over previous
//
#include <hip/hip_runtime.h>

#define NUM_USERS 100000
#define NUM_ITEMS 50000
#define EMB 64
#define NUM_EDGES 1250000
#define NNODES (NUM_USERS + NUM_ITEMS)
#define NELEM (NNODES * EMB)      // 9,600,000 floats
#define SCAN_CHUNK 1024
#define NBLK_SCAN ((NNODES + SCAN_CHUNK - 1) / SCAN_CHUNK)   // 147

// ---------------------------------------------------------------------------
// 1. fused histogram + per-edge rank: rank[e] = position within dst bucket
// ---------------------------------------------------------------------------
__global__ void hist_rank_d(const int4* __restrict__ dst4, int* __restrict__ counts,
                            int4* __restrict__ rank4) {
    int i = blockIdx.x * blockDim.x + threadIdx.x;
    if (i < NUM_EDGES / 4) {
        int4 d = dst4[i];
        int4 r;
        r.x = atomicAdd(&counts[d.x], 1);
        r.y = atomicAdd(&counts[d.y], 1);
        r.z = atomicAdd(&counts[d.z], 1);
        r.w = atomicAdd(&counts[d.w], 1);
        rank4[i] = r;
    }
}

// ---------------------------------------------------------------------------
// 2a. per-block sums of 1024-element chunks
// ---------------------------------------------------------------------------
__global__ void scan1_d(const int* __restrict__ counts, int* __restrict__ blksum) {
    __shared__ int lds[256];
    int base = blockIdx.x * SCAN_CHUNK;
    int t = threadIdx.x;
    int s = 0;
#pragma unroll
    for (int j = 0; j < 4; ++j) {
        int i = base + t * 4 + j;
        if (i < NNODES) s += counts[i];
    }
    lds[t] = s;
    __syncthreads();
    for (int off = 128; off > 0; off >>= 1) {
        if (t < off) lds[t] += lds[t + off];
        __syncthreads();
    }
    if (t == 0) blksum[blockIdx.x] = lds[0];
}

// ---------------------------------------------------------------------------
// 2b. exclusive scan of block sums (NBLK_SCAN <= 256), one block
// ---------------------------------------------------------------------------
__global__ void scan2_d(int* __restrict__ blksum) {
    __shared__ int lds[256];
    int t = threadIdx.x;
    int v = (t < NBLK_SCAN) ? blksum[t] : 0;
    lds[t] = v;
    __syncthreads();
    for (int off = 1; off < 256; off <<= 1) {
        int add = (t >= off) ? lds[t - off] : 0;
        __syncthreads();
        lds[t] += add;
        __syncthreads();
    }
    if (t < NBLK_SCAN) blksum[t] = lds[t] - v;   // exclusive
}

// ---------------------------------------------------------------------------
// 2c. offsets + per-node scale tables (counts preserved as degree)
//     dis = deg^{-1/2}, invdeg = 1/deg, rdis = deg^{+1/2}  (0 when deg==0)
// ---------------------------------------------------------------------------
__global__ void scan3_d(const int* __restrict__ counts, const int* __restrict__ blksum,
                        int* __restrict__ offs, float* __restrict__ dis,
                        float* __restrict__ invdeg, float* __restrict__ rdis) {
    __shared__ int lds[256];
    int base = blockIdx.x * SCAN_CHUNK;
    int t = threadIdx.x;
    int c[4];
    int s = 0;
#pragma unroll
    for (int j = 0; j < 4; ++j) {
        int i = base + t * 4 + j;
        c[j] = (i < NNODES) ? counts[i] : 0;
        s += c[j];
    }
    lds[t] = s;
    __syncthreads();
    for (int off = 1; off < 256; off <<= 1) {
        int add = (t >= off) ? lds[t - off] : 0;
        __syncthreads();
        lds[t] += add;
        __syncthreads();
    }
    int run = blksum[blockIdx.x] + lds[t] - s;   // exclusive prefix of first elem
#pragma unroll
    for (int j = 0; j < 4; ++j) {
        int i = base + t * 4 + j;
        if (i < NNODES) {
            float fc = (float)c[j];
            offs[i]   = run;
            dis[i]    = (c[j] > 0) ? (1.0f / sqrtf(fc)) : 0.0f;
            invdeg[i] = (c[j] > 0) ? (1.0f / fc) : 0.0f;
            rdis[i]   = (c[j] > 0) ? sqrtf(fc) : 0.0f;
            run += c[j];
        }
    }
}

// ---------------------------------------------------------------------------
// 3. atomic-free scatter: entries[offs[dst]+rank] = src
// ---------------------------------------------------------------------------
__global__ void scatter_d(const int4* __restrict__ src4, const int4* __restrict__ dst4,
                          const int4* __restrict__ rank4, const int* __restrict__ offs,
                          int* __restrict__ entries) {
    int i = blockIdx.x * blockDim.x + threadIdx.x;
    if (i < NUM_EDGES / 4) {
        int4 s = src4[i];
        int4 d = dst4[i];
        int4 r = rank4[i];
        entries[offs[d.x] + r.x] = s.x;
        entries[offs[d.y] + r.y] = s.y;
        entries[offs[d.z] + r.z] = s.z;
        entries[offs[d.w] + r.w] = s.w;
    }
}

// ---------------------------------------------------------------------------
// 4. pull hop: one 16-lane group per node (4 nodes/wave), lane owns 4 emb dims.
//    Entry indices are read per-group (same address within group -> HW
//    broadcast); rows gathered as float4, 4-deep unrolled into independent
//    accumulators; no cross-lane reduction needed.
//    MODE 0: y1[d]   = invdeg[d] * Σ dis[s]·x0[s]      (gathers uw/iw directly)
//    MODE 1: y2[d]   = invdeg[d] * Σ y1[s]
//    MODE 2: out[d]  = 0.25*(x0 + rdis·(y1+y2) + dis·Σ y2[s])
// ---------------------------------------------------------------------------
__device__ __forceinline__ void gaccy_d(float4& a, const float4* __restrict__ y,
                                        int s, int c) {
    float4 v = y[((size_t)s << 4) + c];           // row s = 16 float4s (256B)
    a.x += v.x; a.y += v.y; a.z += v.z; a.w += v.w;
}

__device__ __forceinline__ void gacc0_d(float4& a, const float* __restrict__ uw,
                                        const float* __restrict__ iw,
                                        const float* __restrict__ dis, int s, int c) {
    float w = dis[s];
    const float* xr = (s < NUM_USERS) ? (uw + ((size_t)s << 6))
                                      : (iw + ((size_t)(s - NUM_USERS) << 6));
    float4 v = *(const float4*)(xr + (c << 2));
    a.x = fmaf(w, v.x, a.x); a.y = fmaf(w, v.y, a.y);
    a.z = fmaf(w, v.z, a.z); a.w = fmaf(w, v.w, a.w);
}

template <int MODE>
__global__ __launch_bounds__(256)
void pull_d(const int* __restrict__ entries, const int* __restrict__ offs,
            const int* __restrict__ deg, const float* __restrict__ invdeg,
            const float4* __restrict__ yin,         // MODE 1: y1, MODE 2: y2
            const float* __restrict__ dis, const float* __restrict__ rdis,
            const float4* __restrict__ y1,          // MODE 2 only
            const float* __restrict__ uw, const float* __restrict__ iw,
            float4* __restrict__ out) {
    int gid = blockIdx.x * blockDim.x + threadIdx.x;
    int n   = gid >> 4;                           // node per 16-lane group
    if (n >= NNODES) return;
    int c   = gid & 15;                           // float4 chunk within row

    const int* eb = entries + offs[n];
    int dg = deg[n];

    float4 a0 = {0,0,0,0}, a1 = {0,0,0,0}, a2 = {0,0,0,0}, a3 = {0,0,0,0};

    int j = 0;
    for (; j + 4 <= dg; j += 4) {
        int s0 = eb[j], s1 = eb[j + 1], s2 = eb[j + 2], s3 = eb[j + 3];
        if (MODE == 0) {
            gacc0_d(a0, uw, iw, dis, s0, c);
            gacc0_d(a1, uw, iw, dis, s1, c);
            gacc0_d(a2, uw, iw, dis, s2, c);
            gacc0_d(a3, uw, iw, dis, s3, c);
        } else {
            gaccy_d(a0, yin, s0, c);
            gaccy_d(a1, yin, s1, c);
            gaccy_d(a2, yin, s2, c);
            gaccy_d(a3, yin, s3, c);
        }
    }
    for (; j < dg; ++j) {
        int s0 = eb[j];
        if (MODE == 0) gacc0_d(a0, uw, iw, dis, s0, c);
        else           gaccy_d(a0, yin, s0, c);
    }

    float4 a;
    a.x = (a0.x + a1.x) + (a2.x + a3.x);
    a.y = (a0.y + a1.y) + (a2.y + a3.y);
    a.z = (a0.z + a1.z) + (a2.z + a3.z);
    a.w = (a0.w + a1.w) + (a2.w + a3.w);

    size_t ro = ((size_t)n << 4) + c;             // float4 index of out row chunk
    if (MODE == 2) {
        const float* xrow = (n < NUM_USERS) ? uw + ((size_t)n << 6)
                                            : iw + ((size_t)(n - NUM_USERS) << 6);
        float4 x0v = *(const float4*)(xrow + (c << 2));
        float4 b = y1[ro];
        float4 d2 = yin[ro];                      // yin == y2 here
        float rd = rdis[n], di = dis[n];
        float4 o;
        o.x = 0.25f * (x0v.x + rd * (b.x + d2.x) + di * a.x);
        o.y = 0.25f * (x0v.y + rd * (b.y + d2.y) + di * a.y);
        o.z = 0.25f * (x0v.z + rd * (b.z + d2.z) + di * a.z);
        o.w = 0.25f * (x0v.w + rd * (b.w + d2.w) + di * a.w);
        out[ro] = o;
    } else {
        float iv = invdeg[n];
        a.x *= iv; a.y *= iv; a.z *= iv; a.w *= iv;
        out[ro] = a;
    }
}

extern "C" void kernel_launch(void* const* d_in, const int* in_sizes, int n_in,
                              void* d_out, int out_size, void* d_ws, size_t ws_size,
                              hipStream_t stream) {
    const float* uw  = (const float*)d_in[0];    // [NUM_USERS, EMB]
    const float* iw  = (const float*)d_in[1];    // [NUM_ITEMS, EMB]
    const int*   ei  = (const int*)d_in[2];      // [2, NUM_EDGES]
    const int*   src = ei;
    const int*   dst = ei + NUM_EDGES;

    float* out = (float*)d_out;                  // [NNODES, EMB] fp32

    // workspace layout (~84.3 MB)
    char*  ws      = (char*)d_ws;
    float* y1      = (float*)ws;                              // NELEM floats (38.4 MB)
    float* y2      = y1 + NELEM;                              // NELEM floats (38.4 MB)
    int*   entries = (int*)(y2 + NELEM);                      // NUM_EDGES ints (5 MB)
    int*   counts  = entries + NUM_EDGES;                     // NNODES (stays = degree)
    int*   offs    = counts + NNODES;                         // NNODES
    float* dis     = (float*)(offs + NNODES);                 // NNODES
    float* invdeg  = dis + NNODES;                            // NNODES
    float* rdis    = invdeg + NNODES;                         // NNODES
    int*   blksum  = (int*)(rdis + NNODES);                   // NBLK_SCAN
    int*   rank    = (int*)y1;     // alias: consumed by scatter_d before y1 written

    const int B = 256;
    const int eblk = (NUM_EDGES / 4 + B - 1) / B;             // 1221

    // --- CSR build (rank-fused, atomic-free scatter) ---
    hipMemsetAsync(counts, 0, NNODES * sizeof(int), stream);
    hist_rank_d<<<eblk, B, 0, stream>>>((const int4*)dst, counts, (int4*)rank);
    scan1_d<<<NBLK_SCAN, B, 0, stream>>>(counts, blksum);
    scan2_d<<<1, B, 0, stream>>>(blksum);
    scan3_d<<<NBLK_SCAN, B, 0, stream>>>(counts, blksum, offs, dis, invdeg, rdis);
    scatter_d<<<eblk, B, 0, stream>>>((const int4*)src, (const int4*)dst,
                                      (const int4*)rank, offs, entries);

    // --- hops: 16 lanes per node -> NNODES*16 threads ---
    const int pull_blocks = (NNODES * 16 + B - 1) / B;        // 9375
    pull_d<0><<<pull_blocks, B, 0, stream>>>(
        entries, offs, counts, invdeg, nullptr, dis, nullptr,
        nullptr, uw, iw, (float4*)y1);
    pull_d<1><<<pull_blocks, B, 0, stream>>>(
        entries, offs, counts, invdeg, (const float4*)y1, dis, rdis,
        nullptr, nullptr, nullptr, (float4*)y2);
    pull_d<2><<<pull_blocks, B, 0, stream>>>(
        entries, offs, counts, invdeg, (const float4*)y2, dis, rdis,
        (const float4*)y1, uw, iw, (float4*)out);
}